// Round 3
// baseline (189.670 us; speedup 1.0000x reference)
//
#include <hip/hip_runtime.h>

#define BSZN 8
#define TT 4096
#define DIN 512
#define PP 256
#define HHH 256
#define DOUT 512
#define LCH 64              // scan chunk length == row tile
#define NCH (TT / LCH)      // 64 chunks per batch
#define NBLK (BSZN * NCH)   // 512 blocks -> 2/CU co-resident
#define XPS 264             // xp/hsL row stride (bf16 elems), 528 B
#define AST 136             // As row stride (bytes), 64 bf16 + 8 B pad

typedef __attribute__((ext_vector_type(8))) short bf16x8;
typedef __attribute__((ext_vector_type(4))) float f32x4;

#define GLOBAL_AS __attribute__((address_space(1)))
#define LDS_AS __attribute__((address_space(3)))

static __device__ __forceinline__ void gld_lds16(const void* g, void* l) {
  __builtin_amdgcn_global_load_lds((const GLOBAL_AS unsigned int*)g,
                                   (LDS_AS unsigned int*)l, 16, 0, 0);
}

static __device__ __forceinline__ unsigned short f2bf(float x) {
  union { float f; unsigned u; } t{x};
  unsigned r = t.u + 0x7fffu + ((t.u >> 16) & 1u);  // RNE
  return (unsigned short)(r >> 16);
}

static __device__ __forceinline__ float ld_carry(const float* p) {
  return __hip_atomic_load(p, __ATOMIC_RELAXED, __HIP_MEMORY_SCOPE_AGENT);
}

// Tiled-rotated weight layouts (k-major 32-elem tiles, 64 B rows, 16 B slot
// rotated by (row>>1)): LDS frag reads conflict-free, staging stays linear.
// pos = tile*(NROWS*32) + row*32 + (((k>>3)&3 + (row>>1))&3)*8 + (k&7)

// ---------------------------------------------------------------------------
// Prep: PURE ELEMENTWISE (no GEMM, no barriers). Grid = 385:
//   0-127: Wi->Wi_t   128-191: B->B_t (transpose-tile)
// 192-255: C->C_t (transpose-tile)   256-383: Wo->Wo_t   384: zero flags
// ---------------------------------------------------------------------------
__global__ __launch_bounds__(256) void prep_k(
    const float* __restrict__ Wi, const float* __restrict__ Wo,
    const float* __restrict__ Cm, const float* __restrict__ Bm,
    unsigned short* __restrict__ Wi_t, unsigned short* __restrict__ B_t,
    unsigned short* __restrict__ C_t, unsigned short* __restrict__ Wo_t,
    int* __restrict__ flag_g) {
  const int b = blockIdx.x, tid = threadIdx.x;
  if (b < 128) {                       // Wi (256x512): rows=p, k=d
    const int idx = b * 1024 + tid * 4;
    const int row = idx >> 9, d = idx & 511;
    const float4 v = *(const float4*)(Wi + idx);
    uint2 w;
    w.x = (unsigned)f2bf(v.x) | ((unsigned)f2bf(v.y) << 16);
    w.y = (unsigned)f2bf(v.z) | ((unsigned)f2bf(v.w) << 16);
    const int tile = d >> 5, kc = (d >> 3) & 3, s = (kc + (row >> 1)) & 3;
    *(uint2*)(Wi_t + tile * 8192 + row * 32 + s * 8 + (d & 7)) = w;
  } else if (b < 192) {                // B^T (rows=h, k=p): coalesced reads
    const int f = (b - 128) * 256 + tid;
    const int p = f >> 6, h = (f & 63) * 4;
    const float4 v = *(const float4*)(Bm + (size_t)p * HHH + h);
    const float vv[4] = {v.x, v.y, v.z, v.w};
    const int tile = p >> 5, kc = (p >> 3) & 3;
#pragma unroll
    for (int j = 0; j < 4; ++j) {
      const int row = h + j, s = (kc + (row >> 1)) & 3;
      B_t[tile * 8192 + row * 32 + s * 8 + (p & 7)] = f2bf(vv[j]);
    }
  } else if (b < 256) {                // C^T (rows=p, k=h): coalesced reads
    const int f = (b - 192) * 256 + tid;
    const int h = f >> 6, p = (f & 63) * 4;
    const float4 v = *(const float4*)(Cm + (size_t)h * PP + p);
    const float vv[4] = {v.x, v.y, v.z, v.w};
    const int tile = h >> 5, kc = (h >> 3) & 3;
#pragma unroll
    for (int j = 0; j < 4; ++j) {
      const int row = p + j, s = (kc + (row >> 1)) & 3;
      C_t[tile * 8192 + row * 32 + s * 8 + (h & 7)] = f2bf(vv[j]);
    }
  } else if (b < 384) {                // Wo (512x256): rows=o, k=p
    const int idx = (b - 256) * 1024 + tid * 4;
    const int o = idx >> 8, p = idx & 255;
    const float4 v = *(const float4*)(Wo + idx);
    uint2 w;
    w.x = (unsigned)f2bf(v.x) | ((unsigned)f2bf(v.y) << 16);
    w.y = (unsigned)f2bf(v.z) | ((unsigned)f2bf(v.w) << 16);
    const int tile = p >> 5, kc = (p >> 3) & 3, s = (kc + (o >> 1)) & 3;
    *(uint2*)(Wo_t + tile * 16384 + o * 32 + s * 8 + (p & 7)) = w;
  } else {                             // zero lookback flags (ws poisoned!)
    flag_g[tid] = 0;
    flag_g[tid + 256] = 0;
  }
}

// ---------------------------------------------------------------------------
// Mega: one block per (batch, 64-row chunk). 512 blocks, 2/CU co-resident.
// Phases: 1) xW=x@Wi^T  1.5) relu->xp  2) u=xp@B  3) reg-scan + lookback
// 4a) y=hs@C  4b) out=y@Wo^T+bo. First staging tile of each GEMM phase is
// pre-issued into the idle TB buffer during the preceding phase.
// ---------------------------------------------------------------------------
__global__ __launch_bounds__(256, 2) void s4_mega(
    const float* __restrict__ x, const float* __restrict__ a,
    const unsigned short* __restrict__ Wi_t, const float* __restrict__ bi,
    const unsigned short* __restrict__ B_t,
    const unsigned short* __restrict__ C_t,
    const unsigned short* __restrict__ Wo_t, const float* __restrict__ bo,
    float* __restrict__ out, float* __restrict__ carry_g,
    int* __restrict__ flag_g) {
  __shared__ alignas(16) char smem[67584];
  char* As = smem;                       // phase1 x tile [64][AST] (8704 B)
  unsigned short* xp = (unsigned short*)smem;  // [64][XPS] bf16 (33792 B)
  char* TB = smem + 33792;               // staging buffer (32 KB)
  float* PL = (float*)(smem + 66560);    // 256 f32

  const int tid = threadIdx.x, wave = tid >> 6, lane = tid & 63;
  const int l15 = lane & 15, q = lane >> 4;
  const int bc = blockIdx.x, b = bc >> 6, c = bc & (NCH - 1);
  const size_t row0 = (size_t)bc * LCH;
  const int wc = wave * 64;   // wave column base (phases 1,2,4a)

  // fragment offsets
  int wrot[4];                // [256-row] k32 tiles (Wi_t/B_t/C_t), bytes
#pragma unroll
  for (int ni = 0; ni < 4; ++ni) {
    const int r = wc + ni * 16 + l15;
    wrot[ni] = r * 64 + (((q + (r >> 1)) & 3) << 4);
  }
  int crot[2][4];             // [512-row] k32 tiles (Wo_t), bytes
#pragma unroll
  for (int g = 0; g < 2; ++g)
#pragma unroll
    for (int ni = 0; ni < 4; ++ni) {
      const int r = wave * 128 + g * 64 + ni * 16 + l15;
      crot[g][ni] = r * 64 + (((q + (r >> 1)) & 3) << 4);
    }
  int afb[4];                 // As read offsets (bytes)
#pragma unroll
  for (int mi = 0; mi < 4; ++mi) afb[mi] = (mi * 16 + l15) * AST + q * 16;
  int xpb[4];                 // xp/hsL read offsets (elems)
#pragma unroll
  for (int mi = 0; mi < 4; ++mi) xpb[mi] = (mi * 16 + l15) * XPS + q * 8;

  const int sbase = wave * 4096 + lane * 16;  // staging lane offset (16 KB/2)

  // ================= phase 1: xW = x @ Wi^T (64x256) =================
  f32x4 acc[4][4];
#pragma unroll
  for (int i = 0; i < 4; ++i)
#pragma unroll
    for (int j = 0; j < 4; ++j) acc[i][j] = f32x4{0.f, 0.f, 0.f, 0.f};

  float4 xv[4];
#pragma unroll
  for (int i = 0; i < 4; ++i) {
    const int f = i * 256 + tid;
    xv[i] = *(const float4*)(x + (row0 + (f >> 4)) * DIN + (f & 15) * 4);
  }
  for (int t = 0; t < 8; ++t) {  // K-step 64: two k32 tiles per step
#pragma unroll
    for (int i = 0; i < 4; ++i) {  // write prefetched x slab into As
      const int f = i * 256 + tid;
      uint2 w;
      w.x = (unsigned)f2bf(xv[i].x) | ((unsigned)f2bf(xv[i].y) << 16);
      w.y = (unsigned)f2bf(xv[i].z) | ((unsigned)f2bf(xv[i].w) << 16);
      *(uint2*)(As + (f >> 4) * AST + (f & 15) * 8) = w;
    }
    {  // stage Wi tile pair t
      const char* gw = (const char*)Wi_t + t * 32768 + sbase;
#pragma unroll
      for (int i = 0; i < 4; ++i) {
        gld_lds16(gw + i * 1024, TB + sbase + i * 1024);
        gld_lds16(gw + 16384 + i * 1024, TB + 16384 + sbase + i * 1024);
      }
    }
    __syncthreads();
    if (t < 7) {  // prefetch next x slab
#pragma unroll
      for (int i = 0; i < 4; ++i) {
        const int f = i * 256 + tid;
        xv[i] = *(const float4*)(x + (row0 + (f >> 4)) * DIN + (t + 1) * 64 +
                                 (f & 15) * 4);
      }
    }
    bf16x8 af[4][2], bfv[4][2];
#pragma unroll
    for (int mi = 0; mi < 4; ++mi) {
      af[mi][0] = *(const bf16x8*)(As + afb[mi]);
      af[mi][1] = *(const bf16x8*)(As + afb[mi] + 64);
    }
#pragma unroll
    for (int ni = 0; ni < 4; ++ni) {
      bfv[ni][0] = *(const bf16x8*)(TB + wrot[ni]);
      bfv[ni][1] = *(const bf16x8*)(TB + 16384 + wrot[ni]);
    }
#pragma unroll
    for (int kk = 0; kk < 2; ++kk)
#pragma unroll
      for (int mi = 0; mi < 4; ++mi)
#pragma unroll
        for (int ni = 0; ni < 4; ++ni)
          acc[mi][ni] = __builtin_amdgcn_mfma_f32_16x16x32_bf16(
              af[mi][kk], bfv[ni][kk], acc[mi][ni], 0, 0, 0);
    __syncthreads();
  }

  // pre-issue phase-2's first B tile pair (TB idle during relu writes)
  {
    const char* gw = (const char*)B_t + sbase;
#pragma unroll
    for (int i = 0; i < 4; ++i) {
      gld_lds16(gw + i * 1024, TB + sbase + i * 1024);
      gld_lds16(gw + 16384 + i * 1024, TB + 16384 + sbase + i * 1024);
    }
  }

  // ============ phase 1.5: relu+bias -> xp [64][XPS] bf16 ============
#pragma unroll
  for (int ni = 0; ni < 4; ++ni) {
    const int col = wc + ni * 16 + l15;
    const float bb = bi[col];
#pragma unroll
    for (int mi = 0; mi < 4; ++mi)
#pragma unroll
      for (int reg = 0; reg < 4; ++reg) {
        const int row = mi * 16 + q * 4 + reg;
        xp[row * XPS + col] = f2bf(fmaxf(acc[mi][ni][reg] + bb, 0.f));
      }
  }

  // ============ phase 2: u = xp @ B ============
#pragma unroll
  for (int i = 0; i < 4; ++i)
#pragma unroll
    for (int j = 0; j < 4; ++j) acc[i][j] = f32x4{0.f, 0.f, 0.f, 0.f};
  for (int t = 0; t < 4; ++t) {  // K-step 64
    if (t > 0) {
      const char* gw = (const char*)B_t + t * 32768 + sbase;
#pragma unroll
      for (int i = 0; i < 4; ++i) {
        gld_lds16(gw + i * 1024, TB + sbase + i * 1024);
        gld_lds16(gw + 16384 + i * 1024, TB + 16384 + sbase + i * 1024);
      }
    }
    __syncthreads();
    bf16x8 af[4][2], bfv[4][2];
#pragma unroll
    for (int mi = 0; mi < 4; ++mi) {
      af[mi][0] = *(const bf16x8*)(xp + xpb[mi] + t * 64);
      af[mi][1] = *(const bf16x8*)(xp + xpb[mi] + t * 64 + 32);
    }
#pragma unroll
    for (int ni = 0; ni < 4; ++ni) {
      bfv[ni][0] = *(const bf16x8*)(TB + wrot[ni]);
      bfv[ni][1] = *(const bf16x8*)(TB + 16384 + wrot[ni]);
    }
#pragma unroll
    for (int kk = 0; kk < 2; ++kk)
#pragma unroll
      for (int mi = 0; mi < 4; ++mi)
#pragma unroll
        for (int ni = 0; ni < 4; ++ni)
          acc[mi][ni] = __builtin_amdgcn_mfma_f32_16x16x32_bf16(
              af[mi][kk], bfv[ni][kk], acc[mi][ni], 0, 0, 0);
    __syncthreads();
  }

  // ============ phase 3: register scan (zero-init local) ============
  float aC[4], Wz[4];
#pragma unroll
  for (int ni = 0; ni < 4; ++ni) aC[ni] = a[wc + ni * 16 + l15];
#pragma unroll
  for (int ni = 0; ni < 4; ++ni) {
    const float A = aC[ni];
    const float A2 = A * A, A4 = A2 * A2, A8 = A4 * A4, A16 = A8 * A8;
    const float A4q = ((q & 1) ? A4 : 1.f) * ((q & 2) ? A8 : 1.f);
    float W = 0.f;
#pragma unroll
    for (int mi = 0; mi < 4; ++mi) {
      f32x4 v = acc[mi][ni];
      v.y = fmaf(A, v.x, v.y);
      v.z = fmaf(A, v.y, v.z);
      v.w = fmaf(A, v.z, v.w);
      const float E = v.w;
      const float E0 = __shfl(E, l15, 64);
      const float E1 = __shfl(E, l15 + 16, 64);
      const float E2 = __shfl(E, l15 + 32, 64);
      const float E3 = __shfl(E, l15 + 48, 64);
      const float s1 = E0, s2 = fmaf(A4, s1, E1), s3 = fmaf(A4, s2, E2);
      const float s4 = fmaf(A4, s3, E3);
      const float Sq = (q == 0) ? 0.f : (q == 1) ? s1 : (q == 2) ? s2 : s3;
      const float sin_ = fmaf(A4q, W, Sq);
      v.x = fmaf(A, sin_, v.x);
      v.y = fmaf(A2, sin_, v.y);
      v.z = fmaf(A2 * A, sin_, v.z);
      v.w = fmaf(A4, sin_, v.w);
      acc[mi][ni] = v;
      W = fmaf(A16, W, s4);
    }
    Wz[ni] = W;
  }
  // publish carry, then flag
  if (q == 0) {
#pragma unroll
    for (int ni = 0; ni < 4; ++ni)
      __hip_atomic_store(&carry_g[(size_t)bc * HHH + wc + ni * 16 + l15],
                         Wz[ni], __ATOMIC_RELAXED, __HIP_MEMORY_SCOPE_AGENT);
  }
  __syncthreads();
  if (tid == 0) {
    __threadfence();
    __hip_atomic_store(&flag_g[bc], 1, __ATOMIC_RELEASE,
                       __HIP_MEMORY_SCOPE_AGENT);
  }
  // pre-issue phase-4a's first C tile pair (lands during spin/lookback)
  {
    const char* gw = (const char*)C_t + sbase;
#pragma unroll
    for (int i = 0; i < 4; ++i) {
      gld_lds16(gw + i * 1024, TB + sbase + i * 1024);
      gld_lds16(gw + 16384 + i * 1024, TB + 16384 + sbase + i * 1024);
    }
  }
  if (tid < c) {
    while (__hip_atomic_load(&flag_g[b * NCH + tid], __ATOMIC_ACQUIRE,
                             __HIP_MEMORY_SCOPE_AGENT) == 0)
      __builtin_amdgcn_s_sleep(32);
  }
  __syncthreads();
  // per-column incoming state P (thread t -> column t), Horner over carries
  {
    const int colp = tid;
    const float A = a[colp];
    float t1 = A;
#pragma unroll
    for (int j = 0; j < 6; ++j) t1 *= t1;  // A^64
    const float A64 = t1, A128 = A64 * A64, A256 = A128 * A128;
    const float A512 = A256 * A256;
    const float* cg = carry_g + (size_t)b * NCH * HHH + colp;
    float P = 0.f;
    int j = 0;
    for (; j + 8 <= c; j += 8) {  // 8 loads in flight per iteration
      float cv[8];
#pragma unroll
      for (int i = 0; i < 8; ++i) cv[i] = ld_carry(cg + (size_t)(j + i) * HHH);
      float u = cv[0];
#pragma unroll
      for (int i = 1; i < 8; ++i) u = fmaf(A64, u, cv[i]);
      P = fmaf(A512, P, u);
    }
    for (; j < c; ++j) P = fmaf(A64, P, ld_carry(cg + (size_t)j * HHH));
    PL[colp] = P;
  }
  __syncthreads();
  // fixup: h_row += A^(row+1) * P
#pragma unroll
  for (int ni = 0; ni < 4; ++ni) {
    const float A = aC[ni];
    const float A2 = A * A, A4 = A2 * A2, A8 = A4 * A4, A16 = A8 * A8;
    const float A4q = ((q & 1) ? A4 : 1.f) * ((q & 2) ? A8 : 1.f);
    const float P = PL[wc + ni * 16 + l15];
    float fm = A4q * A * P;
#pragma unroll
    for (int mi = 0; mi < 4; ++mi) {
      f32x4 v = acc[mi][ni];
      v.x += fm;
      v.y = fmaf(A, fm, v.y);
      v.z = fmaf(A2, fm, v.z);
      v.w = fmaf(A2 * A, fm, v.w);
      acc[mi][ni] = v;
      fm *= A16;
    }
  }
  __syncthreads();  // PL consumed; xp region about to be overwritten

  // ============ phase 4a: y = hs @ C (64x256, K=256) ============
  unsigned short* hsL = (unsigned short*)smem;  // [64][XPS] bf16
#pragma unroll
  for (int ni = 0; ni < 4; ++ni) {
    const int col = wc + ni * 16 + l15;
#pragma unroll
    for (int mi = 0; mi < 4; ++mi)
#pragma unroll
      for (int reg = 0; reg < 4; ++reg)
        hsL[(mi * 16 + q * 4 + reg) * XPS + col] = f2bf(acc[mi][ni][reg]);
  }
#pragma unroll
  for (int i = 0; i < 4; ++i)
#pragma unroll
    for (int j = 0; j < 4; ++j) acc[i][j] = f32x4{0.f, 0.f, 0.f, 0.f};
  for (int t = 0; t < 4; ++t) {  // K-step 64
    if (t > 0) {
      const char* gw = (const char*)C_t + t * 32768 + sbase;
#pragma unroll
      for (int i = 0; i < 4; ++i) {
        gld_lds16(gw + i * 1024, TB + sbase + i * 1024);
        gld_lds16(gw + 16384 + i * 1024, TB + 16384 + sbase + i * 1024);
      }
    }
    __syncthreads();
    bf16x8 af[4][2], bfv[4][2];
#pragma unroll
    for (int mi = 0; mi < 4; ++mi) {
      af[mi][0] = *(const bf16x8*)(hsL + xpb[mi] + t * 64);
      af[mi][1] = *(const bf16x8*)(hsL + xpb[mi] + t * 64 + 32);
    }
#pragma unroll
    for (int ni = 0; ni < 4; ++ni) {
      bfv[ni][0] = *(const bf16x8*)(TB + wrot[ni]);
      bfv[ni][1] = *(const bf16x8*)(TB + 16384 + wrot[ni]);
    }
#pragma unroll
    for (int kk = 0; kk < 2; ++kk)
#pragma unroll
      for (int mi = 0; mi < 4; ++mi)
#pragma unroll
        for (int ni = 0; ni < 4; ++ni)
          acc[mi][ni] = __builtin_amdgcn_mfma_f32_16x16x32_bf16(
              af[mi][kk], bfv[ni][kk], acc[mi][ni], 0, 0, 0);
    __syncthreads();
  }

  // pre-issue phase-4b's first Wo tile (TB idle during y writes)
  {
    const char* gw = (const char*)Wo_t + wave * 8192 + lane * 16;
#pragma unroll
    for (int i = 0; i < 8; ++i)
      gld_lds16(gw + i * 1024, TB + wave * 8192 + lane * 16 + i * 1024);
  }
  // y -> hsL (no bias; bo applies after Wo)
#pragma unroll
  for (int ni = 0; ni < 4; ++ni) {
    const int col = wc + ni * 16 + l15;
#pragma unroll
    for (int mi = 0; mi < 4; ++mi)
#pragma unroll
      for (int reg = 0; reg < 4; ++reg)
        hsL[(mi * 16 + q * 4 + reg) * XPS + col] = f2bf(acc[mi][ni][reg]);
  }

  // ============ phase 4b: out = y @ Wo^T + bo (K=256) ============
  f32x4 oacc[2][4][4];
#pragma unroll
  for (int g = 0; g < 2; ++g)
#pragma unroll
    for (int i = 0; i < 4; ++i)
#pragma unroll
      for (int j = 0; j < 4; ++j) oacc[g][i][j] = f32x4{0.f, 0.f, 0.f, 0.f};
  for (int t = 0; t < 8; ++t) {  // K-step 32, tile [512][32] = 32 KB
    if (t > 0) {
      const char* gw = (const char*)Wo_t + t * 32768 + wave * 8192 + lane * 16;
#pragma unroll
      for (int i = 0; i < 8; ++i)
        gld_lds16(gw + i * 1024, TB + wave * 8192 + lane * 16 + i * 1024);
    }
    __syncthreads();
    bf16x8 af[4], bfv[2][4];
#pragma unroll
    for (int mi = 0; mi < 4; ++mi)
      af[mi] = *(const bf16x8*)(hsL + xpb[mi] + t * 32);
#pragma unroll
    for (int g = 0; g < 2; ++g)
#pragma unroll
      for (int ni = 0; ni < 4; ++ni)
        bfv[g][ni] = *(const bf16x8*)(TB + crot[g][ni]);
#pragma unroll
    for (int g = 0; g < 2; ++g)
#pragma unroll
      for (int mi = 0; mi < 4; ++mi)
#pragma unroll
        for (int ni = 0; ni < 4; ++ni)
          oacc[g][mi][ni] = __builtin_amdgcn_mfma_f32_16x16x32_bf16(
              af[mi], bfv[g][ni], oacc[g][mi][ni], 0, 0, 0);
    __syncthreads();
  }
#pragma unroll
  for (int g = 0; g < 2; ++g)
#pragma unroll
    for (int ni = 0; ni < 4; ++ni) {
      const int ocol = wave * 128 + g * 64 + ni * 16 + l15;
      const float bb = bo[ocol];
#pragma unroll
      for (int mi = 0; mi < 4; ++mi)
#pragma unroll
        for (int reg = 0; reg < 4; ++reg) {
          const int row = mi * 16 + q * 4 + reg;
          out[(row0 + row) * DOUT + ocol] = oacc[g][mi][ni][reg] + bb;
        }
    }
}

// ---------------------------------------------------------------------------
extern "C" void kernel_launch(void* const* d_in, const int* in_sizes, int n_in,
                              void* d_out, int out_size, void* d_ws,
                              size_t ws_size, hipStream_t stream) {
  const float* x  = (const float*)d_in[0];
  const float* a  = (const float*)d_in[1];
  const float* Bm = (const float*)d_in[2];
  const float* Cm = (const float*)d_in[3];
  const float* Wi = (const float*)d_in[4];
  const float* bi = (const float*)d_in[5];
  const float* Wo = (const float*)d_in[6];
  const float* bo = (const float*)d_in[7];
  float* out = (float*)d_out;

  char* ws = (char*)d_ws;
  unsigned short* Wi_t = (unsigned short*)ws; ws += (size_t)PP * DIN * 2;
  unsigned short* B_t  = (unsigned short*)ws; ws += (size_t)HHH * PP * 2;
  unsigned short* C_t  = (unsigned short*)ws; ws += (size_t)HHH * PP * 2;
  unsigned short* Wo_t = (unsigned short*)ws; ws += (size_t)DOUT * PP * 2;
  float* carry_g = (float*)ws; ws += (size_t)NBLK * HHH * 4;
  int* flag_g = (int*)ws;

  prep_k<<<385, 256, 0, stream>>>(Wi, Wo, Cm, Bm, Wi_t, B_t, C_t, Wo_t,
                                  flag_g);
  s4_mega<<<NBLK, 256, 0, stream>>>(x, a, Wi_t, bi, B_t, C_t, Wo_t, bo, out,
                                    carry_g, flag_g);
}

// Round 4
// 172.522 us; speedup vs baseline: 1.0994x; 1.0994x over previous
//
#include <hip/hip_runtime.h>

#define BSZN 8
#define TT 4096
#define DIN 512
#define PP 256
#define HHH 256
#define DOUT 512
#define LCH 64              // scan chunk length == row tile
#define NCH (TT / LCH)      // 64 chunks per batch
#define NBLK (BSZN * NCH)   // 512 blocks -> 2/CU co-resident
#define XPS 264             // xp/hsL row stride (bf16 elems), 528 B
#define AST 136             // As row stride (bytes), 64 bf16 + 8 B pad

typedef __attribute__((ext_vector_type(8))) short bf16x8;
typedef __attribute__((ext_vector_type(4))) float f32x4;

#define GLOBAL_AS __attribute__((address_space(1)))
#define LDS_AS __attribute__((address_space(3)))

static __device__ __forceinline__ void gld_lds16(const void* g, void* l) {
  __builtin_amdgcn_global_load_lds((const GLOBAL_AS unsigned int*)g,
                                   (LDS_AS unsigned int*)l, 16, 0, 0);
}

static __device__ __forceinline__ unsigned short f2bf(float x) {
  union { float f; unsigned u; } t{x};
  unsigned r = t.u + 0x7fffu + ((t.u >> 16) & 1u);  // RNE
  return (unsigned short)(r >> 16);
}

// Tiled-rotated weight layouts (k-major 32-elem tiles, 64 B rows, 16 B slot
// rotated by (row>>1)): LDS frag reads conflict-free, staging stays linear.
// pos = tile*(NROWS*32) + row*32 + (((k>>3)&3 + (row>>1))&3)*8 + (k&7)

// ---------------------------------------------------------------------------
// Prep: PURE ELEMENTWISE. Grid = 384:
//   0-127: Wi->Wi_t  128-191: B->B_t  192-255: C->C_t  256-383: Wo->Wo_t
// ---------------------------------------------------------------------------
__global__ __launch_bounds__(256) void prep_k(
    const float* __restrict__ Wi, const float* __restrict__ Wo,
    const float* __restrict__ Cm, const float* __restrict__ Bm,
    unsigned short* __restrict__ Wi_t, unsigned short* __restrict__ B_t,
    unsigned short* __restrict__ C_t, unsigned short* __restrict__ Wo_t) {
  const int b = blockIdx.x, tid = threadIdx.x;
  if (b < 128) {                       // Wi (256x512): rows=p, k=d
    const int idx = b * 1024 + tid * 4;
    const int row = idx >> 9, d = idx & 511;
    const float4 v = *(const float4*)(Wi + idx);
    uint2 w;
    w.x = (unsigned)f2bf(v.x) | ((unsigned)f2bf(v.y) << 16);
    w.y = (unsigned)f2bf(v.z) | ((unsigned)f2bf(v.w) << 16);
    const int tile = d >> 5, kc = (d >> 3) & 3, s = (kc + (row >> 1)) & 3;
    *(uint2*)(Wi_t + tile * 8192 + row * 32 + s * 8 + (d & 7)) = w;
  } else if (b < 192) {                // B^T (rows=h, k=p): coalesced reads
    const int f = (b - 128) * 256 + tid;
    const int p = f >> 6, h = (f & 63) * 4;
    const float4 v = *(const float4*)(Bm + (size_t)p * HHH + h);
    const float vv[4] = {v.x, v.y, v.z, v.w};
    const int tile = p >> 5, kc = (p >> 3) & 3;
#pragma unroll
    for (int j = 0; j < 4; ++j) {
      const int row = h + j, s = (kc + (row >> 1)) & 3;
      B_t[tile * 8192 + row * 32 + s * 8 + (p & 7)] = f2bf(vv[j]);
    }
  } else if (b < 256) {                // C^T (rows=p, k=h): coalesced reads
    const int f = (b - 192) * 256 + tid;
    const int h = f >> 6, p = (f & 63) * 4;
    const float4 v = *(const float4*)(Cm + (size_t)h * PP + p);
    const float vv[4] = {v.x, v.y, v.z, v.w};
    const int tile = h >> 5, kc = (h >> 3) & 3;
#pragma unroll
    for (int j = 0; j < 4; ++j) {
      const int row = p + j, s = (kc + (row >> 1)) & 3;
      C_t[tile * 8192 + row * 32 + s * 8 + (h & 7)] = f2bf(vv[j]);
    }
  } else {                             // Wo (512x256): rows=o, k=p
    const int idx = (b - 256) * 1024 + tid * 4;
    const int o = idx >> 8, p = idx & 255;
    const float4 v = *(const float4*)(Wo + idx);
    uint2 w;
    w.x = (unsigned)f2bf(v.x) | ((unsigned)f2bf(v.y) << 16);
    w.y = (unsigned)f2bf(v.z) | ((unsigned)f2bf(v.w) << 16);
    const int tile = p >> 5, kc = (p >> 3) & 3, s = (kc + (o >> 1)) & 3;
    *(uint2*)(Wo_t + tile * 16384 + o * 32 + s * 8 + (p & 7)) = w;
  }
}

// ---------------------------------------------------------------------------
// Kernel A: phases 1/1.5/2/3 (zero-init scan). NO atomics/fences/spins.
// Writes hs0 (f32, zero-init scan states) and per-chunk carry.
// ---------------------------------------------------------------------------
__global__ __launch_bounds__(256, 2) void s4_scan(
    const float* __restrict__ x, const float* __restrict__ a,
    const unsigned short* __restrict__ Wi_t, const float* __restrict__ bi,
    const unsigned short* __restrict__ B_t, float* __restrict__ hs0_g,
    float* __restrict__ carry_g) {
  __shared__ alignas(16) char smem[66560];
  char* As = smem;                       // phase1 x tile [64][AST] (8704 B)
  unsigned short* xp = (unsigned short*)smem;  // [64][XPS] bf16 (33792 B)
  char* TB = smem + 33792;               // staging buffer (32 KB)

  const int tid = threadIdx.x, wave = tid >> 6, lane = tid & 63;
  const int l15 = lane & 15, q = lane >> 4;
  const int bc = blockIdx.x;
  const size_t row0 = (size_t)bc * LCH;
  const int wc = wave * 64;

  int wrot[4];                // [256-row] k32 tile frag offsets (bytes)
#pragma unroll
  for (int ni = 0; ni < 4; ++ni) {
    const int r = wc + ni * 16 + l15;
    wrot[ni] = r * 64 + (((q + (r >> 1)) & 3) << 4);
  }
  int afb[4];
#pragma unroll
  for (int mi = 0; mi < 4; ++mi) afb[mi] = (mi * 16 + l15) * AST + q * 16;
  int xpb[4];
#pragma unroll
  for (int mi = 0; mi < 4; ++mi) xpb[mi] = (mi * 16 + l15) * XPS + q * 8;

  const int sbase = wave * 4096 + lane * 16;

  // ================= phase 1: xW = x @ Wi^T (64x256) =================
  f32x4 acc[4][4];
#pragma unroll
  for (int i = 0; i < 4; ++i)
#pragma unroll
    for (int j = 0; j < 4; ++j) acc[i][j] = f32x4{0.f, 0.f, 0.f, 0.f};

  float4 xv[4];
#pragma unroll
  for (int i = 0; i < 4; ++i) {
    const int f = i * 256 + tid;
    xv[i] = *(const float4*)(x + (row0 + (f >> 4)) * DIN + (f & 15) * 4);
  }
  for (int t = 0; t < 8; ++t) {  // K-step 64: two k32 tiles per step
#pragma unroll
    for (int i = 0; i < 4; ++i) {
      const int f = i * 256 + tid;
      uint2 w;
      w.x = (unsigned)f2bf(xv[i].x) | ((unsigned)f2bf(xv[i].y) << 16);
      w.y = (unsigned)f2bf(xv[i].z) | ((unsigned)f2bf(xv[i].w) << 16);
      *(uint2*)(As + (f >> 4) * AST + (f & 15) * 8) = w;
    }
    {
      const char* gw = (const char*)Wi_t + t * 32768 + sbase;
#pragma unroll
      for (int i = 0; i < 4; ++i) {
        gld_lds16(gw + i * 1024, TB + sbase + i * 1024);
        gld_lds16(gw + 16384 + i * 1024, TB + 16384 + sbase + i * 1024);
      }
    }
    __syncthreads();
    if (t < 7) {
#pragma unroll
      for (int i = 0; i < 4; ++i) {
        const int f = i * 256 + tid;
        xv[i] = *(const float4*)(x + (row0 + (f >> 4)) * DIN + (t + 1) * 64 +
                                 (f & 15) * 4);
      }
    }
    bf16x8 af[4][2], bfv[4][2];
#pragma unroll
    for (int mi = 0; mi < 4; ++mi) {
      af[mi][0] = *(const bf16x8*)(As + afb[mi]);
      af[mi][1] = *(const bf16x8*)(As + afb[mi] + 64);
    }
#pragma unroll
    for (int ni = 0; ni < 4; ++ni) {
      bfv[ni][0] = *(const bf16x8*)(TB + wrot[ni]);
      bfv[ni][1] = *(const bf16x8*)(TB + 16384 + wrot[ni]);
    }
#pragma unroll
    for (int kk = 0; kk < 2; ++kk)
#pragma unroll
      for (int mi = 0; mi < 4; ++mi)
#pragma unroll
        for (int ni = 0; ni < 4; ++ni)
          acc[mi][ni] = __builtin_amdgcn_mfma_f32_16x16x32_bf16(
              af[mi][kk], bfv[ni][kk], acc[mi][ni], 0, 0, 0);
    __syncthreads();
  }

  // pre-issue phase-2's first B tile pair
  {
    const char* gw = (const char*)B_t + sbase;
#pragma unroll
    for (int i = 0; i < 4; ++i) {
      gld_lds16(gw + i * 1024, TB + sbase + i * 1024);
      gld_lds16(gw + 16384 + i * 1024, TB + 16384 + sbase + i * 1024);
    }
  }

  // ============ phase 1.5: relu+bias -> xp ============
#pragma unroll
  for (int ni = 0; ni < 4; ++ni) {
    const int col = wc + ni * 16 + l15;
    const float bb = bi[col];
#pragma unroll
    for (int mi = 0; mi < 4; ++mi)
#pragma unroll
      for (int reg = 0; reg < 4; ++reg) {
        const int row = mi * 16 + q * 4 + reg;
        xp[row * XPS + col] = f2bf(fmaxf(acc[mi][ni][reg] + bb, 0.f));
      }
  }

  // ============ phase 2: u = xp @ B ============
#pragma unroll
  for (int i = 0; i < 4; ++i)
#pragma unroll
    for (int j = 0; j < 4; ++j) acc[i][j] = f32x4{0.f, 0.f, 0.f, 0.f};
  for (int t = 0; t < 4; ++t) {
    if (t > 0) {
      const char* gw = (const char*)B_t + t * 32768 + sbase;
#pragma unroll
      for (int i = 0; i < 4; ++i) {
        gld_lds16(gw + i * 1024, TB + sbase + i * 1024);
        gld_lds16(gw + 16384 + i * 1024, TB + 16384 + sbase + i * 1024);
      }
    }
    __syncthreads();
    bf16x8 af[4][2], bfv[4][2];
#pragma unroll
    for (int mi = 0; mi < 4; ++mi) {
      af[mi][0] = *(const bf16x8*)(xp + xpb[mi] + t * 64);
      af[mi][1] = *(const bf16x8*)(xp + xpb[mi] + t * 64 + 32);
    }
#pragma unroll
    for (int ni = 0; ni < 4; ++ni) {
      bfv[ni][0] = *(const bf16x8*)(TB + wrot[ni]);
      bfv[ni][1] = *(const bf16x8*)(TB + 16384 + wrot[ni]);
    }
#pragma unroll
    for (int kk = 0; kk < 2; ++kk)
#pragma unroll
      for (int mi = 0; mi < 4; ++mi)
#pragma unroll
        for (int ni = 0; ni < 4; ++ni)
          acc[mi][ni] = __builtin_amdgcn_mfma_f32_16x16x32_bf16(
              af[mi][kk], bfv[ni][kk], acc[mi][ni], 0, 0, 0);
    __syncthreads();
  }

  // ============ phase 3: register scan (zero-init) ============
  float aC[4], Wz[4];
#pragma unroll
  for (int ni = 0; ni < 4; ++ni) aC[ni] = a[wc + ni * 16 + l15];
#pragma unroll
  for (int ni = 0; ni < 4; ++ni) {
    const float A = aC[ni];
    const float A2 = A * A, A4 = A2 * A2, A8 = A4 * A4, A16 = A8 * A8;
    const float A4q = ((q & 1) ? A4 : 1.f) * ((q & 2) ? A8 : 1.f);
    float W = 0.f;
#pragma unroll
    for (int mi = 0; mi < 4; ++mi) {
      f32x4 v = acc[mi][ni];
      v.y = fmaf(A, v.x, v.y);
      v.z = fmaf(A, v.y, v.z);
      v.w = fmaf(A, v.z, v.w);
      const float E = v.w;
      const float E0 = __shfl(E, l15, 64);
      const float E1 = __shfl(E, l15 + 16, 64);
      const float E2 = __shfl(E, l15 + 32, 64);
      const float E3 = __shfl(E, l15 + 48, 64);
      const float s1 = E0, s2 = fmaf(A4, s1, E1), s3 = fmaf(A4, s2, E2);
      const float s4 = fmaf(A4, s3, E3);
      const float Sq = (q == 0) ? 0.f : (q == 1) ? s1 : (q == 2) ? s2 : s3;
      const float sin_ = fmaf(A4q, W, Sq);
      v.x = fmaf(A, sin_, v.x);
      v.y = fmaf(A2, sin_, v.y);
      v.z = fmaf(A2 * A, sin_, v.z);
      v.w = fmaf(A4, sin_, v.w);
      acc[mi][ni] = v;
      W = fmaf(A16, W, s4);
    }
    Wz[ni] = W;
  }
  // plain stores: carry + hs0 (64 B segments across l15)
  if (q == 0) {
#pragma unroll
    for (int ni = 0; ni < 4; ++ni)
      carry_g[(size_t)bc * HHH + wc + ni * 16 + l15] = Wz[ni];
  }
#pragma unroll
  for (int ni = 0; ni < 4; ++ni) {
    const int col = wc + ni * 16 + l15;
#pragma unroll
    for (int mi = 0; mi < 4; ++mi)
#pragma unroll
      for (int reg = 0; reg < 4; ++reg) {
        const int row = mi * 16 + q * 4 + reg;
        hs0_g[(row0 + row) * HHH + col] = acc[mi][ni][reg];
      }
  }
}

// ---------------------------------------------------------------------------
// Kernel B: per-batch prefix over chunk carries. 8 blocks x 256 threads.
// P[b][c][h] = state entering chunk c = sum_{j<c} A64^(c-1-j) * carry[b][j][h]
// ---------------------------------------------------------------------------
__global__ __launch_bounds__(256) void s4_prefix(
    const float* __restrict__ a, const float* __restrict__ carry_g,
    float* __restrict__ P_g) {
  const int b = blockIdx.x, t = threadIdx.x;
  float A = a[t];
#pragma unroll
  for (int j = 0; j < 6; ++j) A *= A;  // A^64
  const float* cg = carry_g + (size_t)b * NCH * HHH + t;
  float* pg = P_g + (size_t)b * NCH * HHH + t;
  float cv[NCH];
#pragma unroll
  for (int c = 0; c < NCH; ++c) cv[c] = cg[(size_t)c * HHH];
  float P = 0.f;
#pragma unroll
  for (int c = 0; c < NCH; ++c) {
    pg[(size_t)c * HHH] = P;
    P = fmaf(A, P, cv[c]);
  }
}

// ---------------------------------------------------------------------------
// Kernel C: fixup (hs = hs0 + A^(row+1)*P) then 4a) y=hs@C  4b) out=y@Wo^T+bo
// ---------------------------------------------------------------------------
__global__ __launch_bounds__(256, 2) void s4_out(
    const float* __restrict__ a, const float* __restrict__ hs0_g,
    const float* __restrict__ P_g, const unsigned short* __restrict__ C_t,
    const unsigned short* __restrict__ Wo_t, const float* __restrict__ bo,
    float* __restrict__ out) {
  __shared__ alignas(16) char smem[66560];
  unsigned short* hsL = (unsigned short*)smem;  // [64][XPS] bf16 (33792 B)
  char* TB = smem + 33792;                      // staging buffer (32 KB)

  const int tid = threadIdx.x, wave = tid >> 6, lane = tid & 63;
  const int l15 = lane & 15, q = lane >> 4;
  const int bc = blockIdx.x;
  const size_t row0 = (size_t)bc * LCH;
  const int wc = wave * 64;

  int wrot[4];
#pragma unroll
  for (int ni = 0; ni < 4; ++ni) {
    const int r = wc + ni * 16 + l15;
    wrot[ni] = r * 64 + (((q + (r >> 1)) & 3) << 4);
  }
  int crot[2][4];
#pragma unroll
  for (int g = 0; g < 2; ++g)
#pragma unroll
    for (int ni = 0; ni < 4; ++ni) {
      const int r = wave * 128 + g * 64 + ni * 16 + l15;
      crot[g][ni] = r * 64 + (((q + (r >> 1)) & 3) << 4);
    }
  int xpb[4];
#pragma unroll
  for (int mi = 0; mi < 4; ++mi) xpb[mi] = (mi * 16 + l15) * XPS + q * 8;

  const int sbase = wave * 4096 + lane * 16;

  // pre-issue 4a's first C tile pair (hides under hs0/P loads + fixup)
  {
    const char* gw = (const char*)C_t + sbase;
#pragma unroll
    for (int i = 0; i < 4; ++i) {
      gld_lds16(gw + i * 1024, TB + sbase + i * 1024);
      gld_lds16(gw + 16384 + i * 1024, TB + 16384 + sbase + i * 1024);
    }
  }

  // load hs0 + P, apply fixup
  f32x4 acc[4][4];
#pragma unroll
  for (int ni = 0; ni < 4; ++ni) {
    const int col = wc + ni * 16 + l15;
#pragma unroll
    for (int mi = 0; mi < 4; ++mi)
#pragma unroll
      for (int reg = 0; reg < 4; ++reg)
        acc[mi][ni][reg] = hs0_g[(row0 + mi * 16 + q * 4 + reg) * HHH + col];
  }
#pragma unroll
  for (int ni = 0; ni < 4; ++ni) {
    const int col = wc + ni * 16 + l15;
    const float A = a[col];
    const float P = P_g[(size_t)bc * HHH + col];
    const float A2 = A * A, A4 = A2 * A2, A8 = A4 * A4, A16 = A8 * A8;
    const float A4q = ((q & 1) ? A4 : 1.f) * ((q & 2) ? A8 : 1.f);
    float fm = A4q * A * P;  // A^(4q+1) * P
#pragma unroll
    for (int mi = 0; mi < 4; ++mi) {
      f32x4 v = acc[mi][ni];
      v.x += fm;
      v.y = fmaf(A, fm, v.y);
      v.z = fmaf(A2, fm, v.z);
      v.w = fmaf(A2 * A, fm, v.w);
      acc[mi][ni] = v;
      fm *= A16;
    }
  }
  // hs -> hsL bf16
#pragma unroll
  for (int ni = 0; ni < 4; ++ni) {
    const int col = wc + ni * 16 + l15;
#pragma unroll
    for (int mi = 0; mi < 4; ++mi)
#pragma unroll
      for (int reg = 0; reg < 4; ++reg)
        hsL[(mi * 16 + q * 4 + reg) * XPS + col] = f2bf(acc[mi][ni][reg]);
  }

  // ============ phase 4a: y = hs @ C (K=256) ============
#pragma unroll
  for (int i = 0; i < 4; ++i)
#pragma unroll
    for (int j = 0; j < 4; ++j) acc[i][j] = f32x4{0.f, 0.f, 0.f, 0.f};
  for (int t = 0; t < 4; ++t) {
    if (t > 0) {
      const char* gw = (const char*)C_t + t * 32768 + sbase;
#pragma unroll
      for (int i = 0; i < 4; ++i) {
        gld_lds16(gw + i * 1024, TB + sbase + i * 1024);
        gld_lds16(gw + 16384 + i * 1024, TB + 16384 + sbase + i * 1024);
      }
    }
    __syncthreads();
    bf16x8 af[4][2], bfv[4][2];
#pragma unroll
    for (int mi = 0; mi < 4; ++mi) {
      af[mi][0] = *(const bf16x8*)(hsL + xpb[mi] + t * 64);
      af[mi][1] = *(const bf16x8*)(hsL + xpb[mi] + t * 64 + 32);
    }
#pragma unroll
    for (int ni = 0; ni < 4; ++ni) {
      bfv[ni][0] = *(const bf16x8*)(TB + wrot[ni]);
      bfv[ni][1] = *(const bf16x8*)(TB + 16384 + wrot[ni]);
    }
#pragma unroll
    for (int kk = 0; kk < 2; ++kk)
#pragma unroll
      for (int mi = 0; mi < 4; ++mi)
#pragma unroll
        for (int ni = 0; ni < 4; ++ni)
          acc[mi][ni] = __builtin_amdgcn_mfma_f32_16x16x32_bf16(
              af[mi][kk], bfv[ni][kk], acc[mi][ni], 0, 0, 0);
    __syncthreads();
  }

  // pre-issue 4b's first Wo tile
  {
    const char* gw = (const char*)Wo_t + wave * 8192 + lane * 16;
#pragma unroll
    for (int i = 0; i < 8; ++i)
      gld_lds16(gw + i * 1024, TB + wave * 8192 + lane * 16 + i * 1024);
  }
  // y -> hsL (no bias; bo applies after Wo)
#pragma unroll
  for (int ni = 0; ni < 4; ++ni) {
    const int col = wc + ni * 16 + l15;
#pragma unroll
    for (int mi = 0; mi < 4; ++mi)
#pragma unroll
      for (int reg = 0; reg < 4; ++reg)
        hsL[(mi * 16 + q * 4 + reg) * XPS + col] = f2bf(acc[mi][ni][reg]);
  }

  // ============ phase 4b: out = y @ Wo^T + bo (K=256) ============
  f32x4 oacc[2][4][4];
#pragma unroll
  for (int g = 0; g < 2; ++g)
#pragma unroll
    for (int i = 0; i < 4; ++i)
#pragma unroll
      for (int j = 0; j < 4; ++j) oacc[g][i][j] = f32x4{0.f, 0.f, 0.f, 0.f};
  for (int t = 0; t < 8; ++t) {
    if (t > 0) {
      const char* gw = (const char*)Wo_t + t * 32768 + wave * 8192 + lane * 16;
#pragma unroll
      for (int i = 0; i < 8; ++i)
        gld_lds16(gw + i * 1024, TB + wave * 8192 + lane * 16 + i * 1024);
    }
    __syncthreads();
    bf16x8 af[4], bfv[2][4];
#pragma unroll
    for (int mi = 0; mi < 4; ++mi)
      af[mi] = *(const bf16x8*)(hsL + xpb[mi] + t * 32);
#pragma unroll
    for (int g = 0; g < 2; ++g)
#pragma unroll
      for (int ni = 0; ni < 4; ++ni)
        bfv[g][ni] = *(const bf16x8*)(TB + crot[g][ni]);
#pragma unroll
    for (int g = 0; g < 2; ++g)
#pragma unroll
      for (int mi = 0; mi < 4; ++mi)
#pragma unroll
        for (int ni = 0; ni < 4; ++ni)
          oacc[g][mi][ni] = __builtin_amdgcn_mfma_f32_16x16x32_bf16(
              af[mi], bfv[g][ni], oacc[g][mi][ni], 0, 0, 0);
    __syncthreads();
  }
#pragma unroll
  for (int g = 0; g < 2; ++g)
#pragma unroll
    for (int ni = 0; ni < 4; ++ni) {
      const int ocol = wave * 128 + g * 64 + ni * 16 + l15;
      const float bb = bo[ocol];
#pragma unroll
      for (int mi = 0; mi < 4; ++mi)
#pragma unroll
        for (int reg = 0; reg < 4; ++reg) {
          const int row = mi * 16 + q * 4 + reg;
          out[(row0 + row) * DOUT + ocol] = oacc[g][mi][ni][reg] + bb;
        }
    }
}

// ---------------------------------------------------------------------------
extern "C" void kernel_launch(void* const* d_in, const int* in_sizes, int n_in,
                              void* d_out, int out_size, void* d_ws,
                              size_t ws_size, hipStream_t stream) {
  const float* x  = (const float*)d_in[0];
  const float* a  = (const float*)d_in[1];
  const float* Bm = (const float*)d_in[2];
  const float* Cm = (const float*)d_in[3];
  const float* Wi = (const float*)d_in[4];
  const float* bi = (const float*)d_in[5];
  const float* Wo = (const float*)d_in[6];
  const float* bo = (const float*)d_in[7];
  float* out = (float*)d_out;

  char* ws = (char*)d_ws;
  unsigned short* Wi_t = (unsigned short*)ws; ws += (size_t)PP * DIN * 2;
  unsigned short* B_t  = (unsigned short*)ws; ws += (size_t)HHH * PP * 2;
  unsigned short* C_t  = (unsigned short*)ws; ws += (size_t)HHH * PP * 2;
  unsigned short* Wo_t = (unsigned short*)ws; ws += (size_t)DOUT * PP * 2;
  float* carry_g = (float*)ws; ws += (size_t)NBLK * HHH * 4;
  float* P_g     = (float*)ws; ws += (size_t)NBLK * HHH * 4;
  float* hs0_g   = (float*)ws;  // 32 MB: [Bsz*T][H] f32

  prep_k<<<384, 256, 0, stream>>>(Wi, Wo, Cm, Bm, Wi_t, B_t, C_t, Wo_t);
  s4_scan<<<NBLK, 256, 0, stream>>>(x, a, Wi_t, bi, B_t, hs0_g, carry_g);
  s4_prefix<<<BSZN, 256, 0, stream>>>(a, carry_g, P_g);
  s4_out<<<NBLK, 256, 0, stream>>>(a, hs0_g, P_g, C_t, Wo_t, bo, out);
}

// Round 5
// 161.393 us; speedup vs baseline: 1.1752x; 1.0690x over previous
//
#include <hip/hip_runtime.h>

#define BSZN 8
#define TT 4096
#define DIN 512
#define PP 256
#define HHH 256
#define DOUT 512
#define LCH 64              // scan chunk length == row tile
#define NCH (TT / LCH)      // 64 chunks per batch
#define NBLK (BSZN * NCH)   // 512 blocks -> 2/CU co-resident
#define XTS 520             // xs row stride (bf16 elems) for full x tile
#define XPS 264             // xp/hsL row stride (bf16 elems)

typedef __attribute__((ext_vector_type(8))) short bf16x8;
typedef __attribute__((ext_vector_type(4))) float f32x4;

static __device__ __forceinline__ unsigned short f2bf(float x) {
  union { float f; unsigned u; } t{x};
  unsigned r = t.u + 0x7fffu + ((t.u >> 16) & 1u);  // RNE
  return (unsigned short)(r >> 16);
}

// Tiled-rotated weight layouts (k-major 32-elem tiles, 64 B rows, 16 B slot
// rotated by (row>>1)). Key property: a wave's bf16x8 fragment read of rows
// [r0,r0+16) covers EXACTLY the contiguous 1 KB [r0*64, r0*64+1024) -> direct
// per-lane global reads are single-burst coalesced; no LDS staging needed.
// pos = tile*(NROWS*32) + row*32 + (((k>>3)&3 + (row>>1))&3)*8 + (k&7)

// ---------------------------------------------------------------------------
// Prep: PURE ELEMENTWISE. Grid = 384:
//   0-127: Wi->Wi_t  128-191: B->B_t  192-255: C->C_t  256-383: Wo->Wo_t
// ---------------------------------------------------------------------------
__global__ __launch_bounds__(256) void prep_k(
    const float* __restrict__ Wi, const float* __restrict__ Wo,
    const float* __restrict__ Cm, const float* __restrict__ Bm,
    unsigned short* __restrict__ Wi_t, unsigned short* __restrict__ B_t,
    unsigned short* __restrict__ C_t, unsigned short* __restrict__ Wo_t) {
  const int b = blockIdx.x, tid = threadIdx.x;
  if (b < 128) {                       // Wi (256x512): rows=p, k=d
    const int idx = b * 1024 + tid * 4;
    const int row = idx >> 9, d = idx & 511;
    const float4 v = *(const float4*)(Wi + idx);
    uint2 w;
    w.x = (unsigned)f2bf(v.x) | ((unsigned)f2bf(v.y) << 16);
    w.y = (unsigned)f2bf(v.z) | ((unsigned)f2bf(v.w) << 16);
    const int tile = d >> 5, kc = (d >> 3) & 3, s = (kc + (row >> 1)) & 3;
    *(uint2*)(Wi_t + tile * 8192 + row * 32 + s * 8 + (d & 7)) = w;
  } else if (b < 192) {                // B^T (rows=h, k=p): coalesced reads
    const int f = (b - 128) * 256 + tid;
    const int p = f >> 6, h = (f & 63) * 4;
    const float4 v = *(const float4*)(Bm + (size_t)p * HHH + h);
    const float vv[4] = {v.x, v.y, v.z, v.w};
    const int tile = p >> 5, kc = (p >> 3) & 3;
#pragma unroll
    for (int j = 0; j < 4; ++j) {
      const int row = h + j, s = (kc + (row >> 1)) & 3;
      B_t[tile * 8192 + row * 32 + s * 8 + (p & 7)] = f2bf(vv[j]);
    }
  } else if (b < 256) {                // C^T (rows=p, k=h): coalesced reads
    const int f = (b - 192) * 256 + tid;
    const int h = f >> 6, p = (f & 63) * 4;
    const float4 v = *(const float4*)(Cm + (size_t)h * PP + p);
    const float vv[4] = {v.x, v.y, v.z, v.w};
    const int tile = h >> 5, kc = (h >> 3) & 3;
#pragma unroll
    for (int j = 0; j < 4; ++j) {
      const int row = p + j, s = (kc + (row >> 1)) & 3;
      C_t[tile * 8192 + row * 32 + s * 8 + (h & 7)] = f2bf(vv[j]);
    }
  } else {                             // Wo (512x256): rows=o, k=p
    const int idx = (b - 256) * 1024 + tid * 4;
    const int o = idx >> 8, p = idx & 255;
    const float4 v = *(const float4*)(Wo + idx);
    uint2 w;
    w.x = (unsigned)f2bf(v.x) | ((unsigned)f2bf(v.y) << 16);
    w.y = (unsigned)f2bf(v.z) | ((unsigned)f2bf(v.w) << 16);
    const int tile = p >> 5, kc = (p >> 3) & 3, s = (kc + (o >> 1)) & 3;
    *(uint2*)(Wo_t + tile * 16384 + o * 32 + s * 8 + (p & 7)) = w;
  }
}

// ---------------------------------------------------------------------------
// Kernel A: phases 1/1.5/2/3. Barrier-free K-loops: x staged once to LDS,
// all weight fragments read DIRECTLY from L2 (1 KB coalesced per wave instr
// thanks to the tiled-rotated layout). 3 barriers total. No atomics/fences.
// hs0 stored in blocked fragment-native layout (f32x4 per thread, 1 KB/instr).
// ---------------------------------------------------------------------------
__global__ __launch_bounds__(256, 2) void s4_scan(
    const float* __restrict__ x, const float* __restrict__ a,
    const unsigned short* __restrict__ Wi_t, const float* __restrict__ bi,
    const unsigned short* __restrict__ B_t, float* __restrict__ hs0_g,
    float* __restrict__ carry_g) {
  __shared__ alignas(16) char smem[66560];      // xs [64][520] bf16
  unsigned short* xs = (unsigned short*)smem;
  unsigned short* xp = (unsigned short*)smem;   // reuse as [64][264]

  const int tid = threadIdx.x, wave = tid >> 6, lane = tid & 63;
  const int l15 = lane & 15, q = lane >> 4;
  const int bc = blockIdx.x;
  const size_t row0 = (size_t)bc * LCH;
  const int wc = wave * 64;

  int wrot[4];                // [256-row] k32 tile frag offsets (bytes)
#pragma unroll
  for (int ni = 0; ni < 4; ++ni) {
    const int r = wc + ni * 16 + l15;
    wrot[ni] = r * 64 + (((q + (r >> 1)) & 3) << 4);
  }
  int xsb[4];                 // xs frag offsets (bytes)
#pragma unroll
  for (int mi = 0; mi < 4; ++mi) xsb[mi] = (mi * 16 + l15) * (XTS * 2) + q * 16;
  int xpb[4];                 // xp frag offsets (elems)
#pragma unroll
  for (int mi = 0; mi < 4; ++mi) xpb[mi] = (mi * 16 + l15) * XPS + q * 8;

  // ---- stage whole x chunk (64x512 f32 -> bf16), ONE barrier ----
#pragma unroll
  for (int rr = 0; rr < 2; ++rr) {
    float4 xv[16];
#pragma unroll
    for (int i = 0; i < 16; ++i) {
      const int f = rr * 4096 + i * 256 + tid;
      xv[i] = *(const float4*)(x + (row0 + (f >> 7)) * DIN + (f & 127) * 4);
    }
#pragma unroll
    for (int i = 0; i < 16; ++i) {
      const int f = rr * 4096 + i * 256 + tid;
      uint2 w;
      w.x = (unsigned)f2bf(xv[i].x) | ((unsigned)f2bf(xv[i].y) << 16);
      w.y = (unsigned)f2bf(xv[i].z) | ((unsigned)f2bf(xv[i].w) << 16);
      *(uint2*)(xs + (f >> 7) * XTS + (f & 127) * 4) = w;
    }
  }
  __syncthreads();

  // ---- phase 1: xW = x @ Wi^T (64x256), barrier-free ----
  f32x4 acc[4][4];
#pragma unroll
  for (int i = 0; i < 4; ++i)
#pragma unroll
    for (int j = 0; j < 4; ++j) acc[i][j] = f32x4{0.f, 0.f, 0.f, 0.f};
  {
    const char* WiB = (const char*)Wi_t;
    for (int t = 0; t < 8; ++t) {  // K-step 64 = two k32 tiles
      bf16x8 af[4][2], bfv[4][2];
#pragma unroll
      for (int mi = 0; mi < 4; ++mi) {
        af[mi][0] = *(const bf16x8*)((const char*)xs + xsb[mi] + t * 128);
        af[mi][1] = *(const bf16x8*)((const char*)xs + xsb[mi] + t * 128 + 64);
      }
#pragma unroll
      for (int ni = 0; ni < 4; ++ni) {
        bfv[ni][0] = *(const bf16x8*)(WiB + t * 32768 + wrot[ni]);
        bfv[ni][1] = *(const bf16x8*)(WiB + t * 32768 + 16384 + wrot[ni]);
      }
#pragma unroll
      for (int kk = 0; kk < 2; ++kk)
#pragma unroll
        for (int mi = 0; mi < 4; ++mi)
#pragma unroll
          for (int ni = 0; ni < 4; ++ni)
            acc[mi][ni] = __builtin_amdgcn_mfma_f32_16x16x32_bf16(
                af[mi][kk], bfv[ni][kk], acc[mi][ni], 0, 0, 0);
    }
  }
  __syncthreads();  // xs dead; region reused as xp

  // ---- phase 1.5: relu+bias -> xp [64][XPS] ----
#pragma unroll
  for (int ni = 0; ni < 4; ++ni) {
    const int col = wc + ni * 16 + l15;
    const float bb = bi[col];
#pragma unroll
    for (int mi = 0; mi < 4; ++mi)
#pragma unroll
      for (int reg = 0; reg < 4; ++reg) {
        const int row = mi * 16 + q * 4 + reg;
        xp[row * XPS + col] = f2bf(fmaxf(acc[mi][ni][reg] + bb, 0.f));
      }
  }
  __syncthreads();

  // ---- phase 2: u = xp @ B, barrier-free ----
#pragma unroll
  for (int i = 0; i < 4; ++i)
#pragma unroll
    for (int j = 0; j < 4; ++j) acc[i][j] = f32x4{0.f, 0.f, 0.f, 0.f};
  {
    const char* BB = (const char*)B_t;
    for (int t = 0; t < 4; ++t) {
      bf16x8 af[4][2], bfv[4][2];
#pragma unroll
      for (int mi = 0; mi < 4; ++mi) {
        af[mi][0] = *(const bf16x8*)(xp + xpb[mi] + t * 64);
        af[mi][1] = *(const bf16x8*)(xp + xpb[mi] + t * 64 + 32);
      }
#pragma unroll
      for (int ni = 0; ni < 4; ++ni) {
        bfv[ni][0] = *(const bf16x8*)(BB + t * 32768 + wrot[ni]);
        bfv[ni][1] = *(const bf16x8*)(BB + t * 32768 + 16384 + wrot[ni]);
      }
#pragma unroll
      for (int kk = 0; kk < 2; ++kk)
#pragma unroll
        for (int mi = 0; mi < 4; ++mi)
#pragma unroll
          for (int ni = 0; ni < 4; ++ni)
            acc[mi][ni] = __builtin_amdgcn_mfma_f32_16x16x32_bf16(
                af[mi][kk], bfv[ni][kk], acc[mi][ni], 0, 0, 0);
    }
  }

  // ---- phase 3: register scan (zero-init) ----
  float aC[4], Wz[4];
#pragma unroll
  for (int ni = 0; ni < 4; ++ni) aC[ni] = a[wc + ni * 16 + l15];
#pragma unroll
  for (int ni = 0; ni < 4; ++ni) {
    const float A = aC[ni];
    const float A2 = A * A, A4 = A2 * A2, A8 = A4 * A4, A16 = A8 * A8;
    const float A4q = ((q & 1) ? A4 : 1.f) * ((q & 2) ? A8 : 1.f);
    float W = 0.f;
#pragma unroll
    for (int mi = 0; mi < 4; ++mi) {
      f32x4 v = acc[mi][ni];
      v.y = fmaf(A, v.x, v.y);
      v.z = fmaf(A, v.y, v.z);
      v.w = fmaf(A, v.z, v.w);
      const float E = v.w;
      const float E0 = __shfl(E, l15, 64);
      const float E1 = __shfl(E, l15 + 16, 64);
      const float E2 = __shfl(E, l15 + 32, 64);
      const float E3 = __shfl(E, l15 + 48, 64);
      const float s1 = E0, s2 = fmaf(A4, s1, E1), s3 = fmaf(A4, s2, E2);
      const float s4 = fmaf(A4, s3, E3);
      const float Sq = (q == 0) ? 0.f : (q == 1) ? s1 : (q == 2) ? s2 : s3;
      const float sin_ = fmaf(A4q, W, Sq);
      v.x = fmaf(A, sin_, v.x);
      v.y = fmaf(A2, sin_, v.y);
      v.z = fmaf(A2 * A, sin_, v.z);
      v.w = fmaf(A4, sin_, v.w);
      acc[mi][ni] = v;
      W = fmaf(A16, W, s4);
    }
    Wz[ni] = W;
  }
  // carry (plain stores) + hs0 in blocked fragment-native layout
  if (q == 0) {
#pragma unroll
    for (int ni = 0; ni < 4; ++ni)
      carry_g[(size_t)bc * HHH + wc + ni * 16 + l15] = Wz[ni];
  }
#pragma unroll
  for (int ni = 0; ni < 4; ++ni)
#pragma unroll
    for (int mi = 0; mi < 4; ++mi) {
      const size_t idx =
          ((((size_t)bc * 4 + wave) * 16 + ni * 4 + mi) * 64 + lane) * 4;
      *(f32x4*)(hs0_g + idx) = acc[mi][ni];
    }
}

// ---------------------------------------------------------------------------
// Kernel B: per-batch prefix over chunk carries. 8 blocks x 256 threads.
// ---------------------------------------------------------------------------
__global__ __launch_bounds__(256) void s4_prefix(
    const float* __restrict__ a, const float* __restrict__ carry_g,
    float* __restrict__ P_g) {
  const int b = blockIdx.x, t = threadIdx.x;
  float A = a[t];
#pragma unroll
  for (int j = 0; j < 6; ++j) A *= A;  // A^64
  const float* cg = carry_g + (size_t)b * NCH * HHH + t;
  float* pg = P_g + (size_t)b * NCH * HHH + t;
  float cv[NCH];
#pragma unroll
  for (int c = 0; c < NCH; ++c) cv[c] = cg[(size_t)c * HHH];
  float P = 0.f;
#pragma unroll
  for (int c = 0; c < NCH; ++c) {
    pg[(size_t)c * HHH] = P;
    P = fmaf(A, P, cv[c]);
  }
}

// ---------------------------------------------------------------------------
// Kernel C: fixup + 4a (y=hs@C) + 4b (out=y@Wo^T+bo). Barrier-free K-loops
// with direct coalesced C_t/Wo_t fragment reads. 3 barriers total.
// ---------------------------------------------------------------------------
__global__ __launch_bounds__(256, 2) void s4_out(
    const float* __restrict__ a, const float* __restrict__ hs0_g,
    const float* __restrict__ P_g, const unsigned short* __restrict__ C_t,
    const unsigned short* __restrict__ Wo_t, const float* __restrict__ bo,
    float* __restrict__ out) {
  __shared__ alignas(16) char smem[33792];
  unsigned short* hsL = (unsigned short*)smem;  // [64][XPS] bf16

  const int tid = threadIdx.x, wave = tid >> 6, lane = tid & 63;
  const int l15 = lane & 15, q = lane >> 4;
  const int bc = blockIdx.x;
  const size_t row0 = (size_t)bc * LCH;
  const int wc = wave * 64;

  int wrot[4];
#pragma unroll
  for (int ni = 0; ni < 4; ++ni) {
    const int r = wc + ni * 16 + l15;
    wrot[ni] = r * 64 + (((q + (r >> 1)) & 3) << 4);
  }
  int crot[2][4];             // [512-row] k32 tile offsets (Wo_t), bytes
#pragma unroll
  for (int g = 0; g < 2; ++g)
#pragma unroll
    for (int ni = 0; ni < 4; ++ni) {
      const int r = wave * 128 + g * 64 + ni * 16 + l15;
      crot[g][ni] = r * 64 + (((q + (r >> 1)) & 3) << 4);
    }
  int xpb[4];
#pragma unroll
  for (int mi = 0; mi < 4; ++mi) xpb[mi] = (mi * 16 + l15) * XPS + q * 8;

  // ---- load blocked hs0 (coalesced f32x4) + fixup ----
  f32x4 acc[4][4];
#pragma unroll
  for (int ni = 0; ni < 4; ++ni)
#pragma unroll
    for (int mi = 0; mi < 4; ++mi) {
      const size_t idx =
          ((((size_t)bc * 4 + wave) * 16 + ni * 4 + mi) * 64 + lane) * 4;
      acc[mi][ni] = *(const f32x4*)(hs0_g + idx);
    }
#pragma unroll
  for (int ni = 0; ni < 4; ++ni) {
    const int col = wc + ni * 16 + l15;
    const float A = a[col];
    const float P = P_g[(size_t)bc * HHH + col];
    const float A2 = A * A, A4 = A2 * A2, A8 = A4 * A4, A16 = A8 * A8;
    const float A4q = ((q & 1) ? A4 : 1.f) * ((q & 2) ? A8 : 1.f);
    float fm = A4q * A * P;  // A^(4q+1) * P
#pragma unroll
    for (int mi = 0; mi < 4; ++mi) {
      f32x4 v = acc[mi][ni];
      v.x += fm;
      v.y = fmaf(A, fm, v.y);
      v.z = fmaf(A2, fm, v.z);
      v.w = fmaf(A2 * A, fm, v.w);
      acc[mi][ni] = v;
      fm *= A16;
    }
  }
  // hs -> hsL bf16
#pragma unroll
  for (int ni = 0; ni < 4; ++ni) {
    const int col = wc + ni * 16 + l15;
#pragma unroll
    for (int mi = 0; mi < 4; ++mi)
#pragma unroll
      for (int reg = 0; reg < 4; ++reg)
        hsL[(mi * 16 + q * 4 + reg) * XPS + col] = f2bf(acc[mi][ni][reg]);
  }
  __syncthreads();

  // ---- phase 4a: y = hs @ C (K=256), barrier-free ----
#pragma unroll
  for (int i = 0; i < 4; ++i)
#pragma unroll
    for (int j = 0; j < 4; ++j) acc[i][j] = f32x4{0.f, 0.f, 0.f, 0.f};
  {
    const char* CB = (const char*)C_t;
    for (int t = 0; t < 4; ++t) {
      bf16x8 af[4][2], bfv[4][2];
#pragma unroll
      for (int mi = 0; mi < 4; ++mi) {
        af[mi][0] = *(const bf16x8*)(hsL + xpb[mi] + t * 64);
        af[mi][1] = *(const bf16x8*)(hsL + xpb[mi] + t * 64 + 32);
      }
#pragma unroll
      for (int ni = 0; ni < 4; ++ni) {
        bfv[ni][0] = *(const bf16x8*)(CB + t * 32768 + wrot[ni]);
        bfv[ni][1] = *(const bf16x8*)(CB + t * 32768 + 16384 + wrot[ni]);
      }
#pragma unroll
      for (int kk = 0; kk < 2; ++kk)
#pragma unroll
        for (int mi = 0; mi < 4; ++mi)
#pragma unroll
          for (int ni = 0; ni < 4; ++ni)
            acc[mi][ni] = __builtin_amdgcn_mfma_f32_16x16x32_bf16(
                af[mi][kk], bfv[ni][kk], acc[mi][ni], 0, 0, 0);
    }
  }
  __syncthreads();  // all waves done reading hsL

  // y -> hsL (no bias; bo applies after Wo)
#pragma unroll
  for (int ni = 0; ni < 4; ++ni) {
    const int col = wc + ni * 16 + l15;
#pragma unroll
    for (int mi = 0; mi < 4; ++mi)
#pragma unroll
      for (int reg = 0; reg < 4; ++reg)
        hsL[(mi * 16 + q * 4 + reg) * XPS + col] = f2bf(acc[mi][ni][reg]);
  }
  __syncthreads();

  // ---- phase 4b: out = y @ Wo^T + bo (K=256), barrier-free ----
  f32x4 oacc[2][4][4];
#pragma unroll
  for (int g = 0; g < 2; ++g)
#pragma unroll
    for (int i = 0; i < 4; ++i)
#pragma unroll
      for (int j = 0; j < 4; ++j) oacc[g][i][j] = f32x4{0.f, 0.f, 0.f, 0.f};
  {
    const char* WoB = (const char*)Wo_t;
    for (int t = 0; t < 8; ++t) {  // K-step 32, [512][32] tiles (32 KB)
      bf16x8 af[4], bfv[2][4];
#pragma unroll
      for (int mi = 0; mi < 4; ++mi)
        af[mi] = *(const bf16x8*)(hsL + xpb[mi] + t * 32);
#pragma unroll
      for (int g = 0; g < 2; ++g)
#pragma unroll
        for (int ni = 0; ni < 4; ++ni)
          bfv[g][ni] = *(const bf16x8*)(WoB + t * 32768 + crot[g][ni]);
#pragma unroll
      for (int g = 0; g < 2; ++g)
#pragma unroll
        for (int mi = 0; mi < 4; ++mi)
#pragma unroll
          for (int ni = 0; ni < 4; ++ni)
            oacc[g][mi][ni] = __builtin_amdgcn_mfma_f32_16x16x32_bf16(
                af[mi], bfv[g][ni], oacc[g][mi][ni], 0, 0, 0);
    }
  }
#pragma unroll
  for (int g = 0; g < 2; ++g)
#pragma unroll
    for (int ni = 0; ni < 4; ++ni) {
      const int ocol = wave * 128 + g * 64 + ni * 16 + l15;
      const float bb = bo[ocol];
#pragma unroll
      for (int mi = 0; mi < 4; ++mi)
#pragma unroll
        for (int reg = 0; reg < 4; ++reg) {
          const int row = mi * 16 + q * 4 + reg;
          out[(row0 + row) * DOUT + ocol] = oacc[g][mi][ni][reg] + bb;
        }
    }
}

// ---------------------------------------------------------------------------
extern "C" void kernel_launch(void* const* d_in, const int* in_sizes, int n_in,
                              void* d_out, int out_size, void* d_ws,
                              size_t ws_size, hipStream_t stream) {
  const float* x  = (const float*)d_in[0];
  const float* a  = (const float*)d_in[1];
  const float* Bm = (const float*)d_in[2];
  const float* Cm = (const float*)d_in[3];
  const float* Wi = (const float*)d_in[4];
  const float* bi = (const float*)d_in[5];
  const float* Wo = (const float*)d_in[6];
  const float* bo = (const float*)d_in[7];
  float* out = (float*)d_out;

  char* ws = (char*)d_ws;
  unsigned short* Wi_t = (unsigned short*)ws; ws += (size_t)PP * DIN * 2;
  unsigned short* B_t  = (unsigned short*)ws; ws += (size_t)HHH * PP * 2;
  unsigned short* C_t  = (unsigned short*)ws; ws += (size_t)HHH * PP * 2;
  unsigned short* Wo_t = (unsigned short*)ws; ws += (size_t)DOUT * PP * 2;
  float* carry_g = (float*)ws; ws += (size_t)NBLK * HHH * 4;
  float* P_g     = (float*)ws; ws += (size_t)NBLK * HHH * 4;
  float* hs0_g   = (float*)ws;  // 32 MB: blocked fragment-native layout

  prep_k<<<384, 256, 0, stream>>>(Wi, Wo, Cm, Bm, Wi_t, B_t, C_t, Wo_t);
  s4_scan<<<NBLK, 256, 0, stream>>>(x, a, Wi_t, bi, B_t, hs0_g, carry_g);
  s4_prefix<<<BSZN, 256, 0, stream>>>(a, carry_g, P_g);
  s4_out<<<NBLK, 256, 0, stream>>>(a, hs0_g, P_g, C_t, Wo_t, bo, out);
}